// Round 19
// baseline (84.219 us; speedup 1.0000x reference)
//
#include <hip/hip_runtime.h>
#include <hip/hip_bf16.h>
#include <math.h>

// B=32, T=256, E=C=256, MIN_CONTEXT=64, FUTURE_STEPS=12
// S0=192, NROW=6144, K=256. G = P·X^T (6144x6144), bucketed exp-sums.
// t in [181,192) are singleton tail buckets; bucket0 = t<181. N_terms=71616.
// Bucket0 accumulated via per-y-panel partial slices (no atomics):
// partial[by][u], by=0..45 (panel by covers t=4by..4by+3; nb0 = #t<181 in panel).

#define NROW 6144
#define TAIL0 181
#define NTERMS 71616.0f
#define LOG2E 1.44269504088896340736f
#define SHIFT2 92.33248261689366f   // 64 * log2(e)

typedef __attribute__((ext_vector_type(8))) short short8;
typedef __attribute__((ext_vector_type(4))) float f32x4;

__device__ __forceinline__ ushort f2bf(float f) {
  union { float f; uint32_t u; } v; v.f = f;
  uint32_t u = v.u;
  return (ushort)((u + 0x7FFFu + ((u >> 16) & 1u)) >> 16);
}
// exp(x - 64) = exp2(x*log2e - 64*log2e)
__device__ __forceinline__ float expsh(float x) {
  return exp2f(fmaf(x, LOG2E, -SHIFT2));
}

// async global->LDS, 16B per lane; lds dst must be wave-uniform base
__device__ __forceinline__ void gload16(const ushort* g, ushort* l) {
  __builtin_amdgcn_global_load_lds((const __attribute__((address_space(1))) void*)g,
                                   (__attribute__((address_space(3))) void*)l, 16, 0, 0);
}

// ---- A0: Wt cast + zero acc/cnt (257 blocks)
__global__ __launch_bounds__(256) void k_castW(const float* __restrict__ W,
                                               ushort* __restrict__ Wt,
                                               float* __restrict__ zbase) {
  int bi = blockIdx.x;
  if (bi < 256) {
    int c = bi, e = threadIdx.x;
    Wt[c * 256 + e] = f2bf(W[e * 256 + c]);
  } else {
    if (threadIdx.x < 2) zbase[threadIdx.x] = 0.f;   // acc, cnt
  }
}

// ---- A1+A2 parallel fusion: blocks [0,1536) cast X; blocks [1536,2304) proj.
__global__ __launch_bounds__(256) void k_projX(const float* __restrict__ emb,
                                               const float* __restrict__ ctx,
                                               const ushort* __restrict__ Wt,
                                               ushort* __restrict__ X,
                                               ushort* __restrict__ P) {
  __shared__ ushort Al[16 * 256];  // 8KB (proj blocks only)
  int bi = blockIdx.x;
  int tid = threadIdx.x;
  if (bi < 1536) {
    // X cast: X[t*32+j][k] = bf16(ctx[j][63+t][k]); 1 f4-chunk per thread
    int idx = bi * 256 + tid;
    int row = idx >> 6, f4 = idx & 63;  // row = t*32+j
    int j = row & 31, t = row >> 5;
    float4 f = *(const float4*)(ctx + ((size_t)(j * 256 + 63 + t)) * 256 + f4 * 4);
    ushort4 o;
    o.x = f2bf(f.x); o.y = f2bf(f.y); o.z = f2bf(f.z); o.w = f2bf(f.w);
    ((ushort4*)(X + (size_t)row * 256))[f4] = o;
    return;
  }
  // ---- proj: P = emb_slice @ W (block = 16-row tile x 128-col half)
  int pb = bi - 1536;                 // 0..767
  int half = pb >= 384 ? 1 : 0;       // col half (384 is NOT pow2 -> no mask!)
  int rt = pb - half * 384;           // 0..383
#pragma unroll
  for (int q = 0; q < 4; ++q) {
    int cc = tid + q * 256;
    int rw = cc >> 6, f4 = cc & 63;
    int u = rt * 16 + rw, b = u / 192, urow = u - b * 192;
    float4 f = *(const float4*)(emb + ((size_t)(b * 256 + 64 + urow)) * 256 + f4 * 4);
    ushort4 o;
    o.x = f2bf(f.x); o.y = f2bf(f.y); o.z = f2bf(f.z); o.w = f2bf(f.w);
    int c8 = f4 >> 1;
    *(ushort4*)&Al[rw * 256 + ((c8 ^ (rw & 7)) * 8) + (f4 & 1) * 4] = o;
  }
  __syncthreads();

  int w = tid >> 6, l = tid & 63;
  int fr = l & 15, kb = l >> 4;
  short8 af[8];
#pragma unroll
  for (int kk = 0; kk < 8; ++kk) {
    int c8 = kk * 4 + kb;
    af[kk] = *(const short8*)&Al[fr * 256 + (c8 ^ (fr & 7)) * 8];
  }
#pragma unroll
  for (int i = 0; i < 2; ++i) {
    int ct = half * 8 + w * 2 + i;
    const short8* bp = (const short8*)(Wt + (size_t)(ct * 16 + fr) * 256);
    f32x4 acc = {0.f, 0.f, 0.f, 0.f};
#pragma unroll
    for (int kk = 0; kk < 8; ++kk)
      acc = __builtin_amdgcn_mfma_f32_16x16x32_bf16(af[kk], bp[kk * 4 + kb], acc, 0, 0, 0);
#pragma unroll
    for (int r = 0; r < 4; ++r)
      P[(size_t)(rt * 16 + kb * 4 + r) * 256 + ct * 16 + fr] = f2bf(acc[r]);
  }
}

// ---- B: G = P·X^T — r17 structure (block 128x128, 1024 thr / 16 waves,
// wave 32x32, acc[2][2], BK=64, double-buffered 64KB LDS, 1 barrier/round,
// 2 blocks/CU) with ATOMIC-FREE epilogue: per-block cross-wc LDS reduce, then
// one plain partial[by][u] store (every entry written -> no zeroing needed).
// LDS rows hold 8 x 16B chunks, slot XOR-swizzled (slot ^ (row&7)) via
// pre-swizzled GLOBAL source addresses -> conflict-free ds_read_b128.
__global__ __launch_bounds__(1024, 8) void k_scores(const ushort* __restrict__ P,
                                                    const ushort* __restrict__ X,
                                                    float* __restrict__ partial,
                                                    float* __restrict__ tail,
                                                    float* __restrict__ pos) {
  __shared__ ushort Albuf[2][128 * 64];   // 2 x 16KB
  __shared__ ushort Blbuf[2][128 * 64];   // 2 x 16KB
  int tid = threadIdx.x;               // 0..1023
  int w = tid >> 6, l = tid & 63;      // w 0..15
  int wr = w >> 2, wc = w & 3;         // wr 0..3, wc 0..3
  int rowbase = blockIdx.x * 128;
  int colbase = blockIdx.y * 128;

  int fr = l & 15, kb = l >> 4;

  // staging geometry: chunk ci = tid (1024 chunks each for A and B).
  // row = ci>>3 (0..127), slot = ci&7 ; src k-chunk = slot ^ (row&7)
  int r0 = tid >> 3;
  int srcc = (tid & 7) ^ (r0 & 7);
  const ushort* gA = P + (size_t)(rowbase + r0) * 256 + srcc * 8;
  const ushort* gB = X + (size_t)(colbase + r0) * 256 + srcc * 8;

  f32x4 acc[2][2];
#pragma unroll
  for (int m = 0; m < 2; ++m)
#pragma unroll
    for (int n = 0; n < 2; ++n) acc[m][n] = {0.f, 0.f, 0.f, 0.f};

  // prologue: stage round 0 into buffer 0
  gload16(gA, &Albuf[0][(size_t)(w * 64) * 8]);
  gload16(gB, &Blbuf[0][(size_t)(w * 64) * 8]);
  __syncthreads();

  for (int kk = 0; kk < 4; ++kk) {
    int cur = kk & 1;
    if (kk < 3) {   // issue next round's stage; in flight across this round
      int kbase = (kk + 1) * 64;
      gload16(gA + kbase, &Albuf[cur ^ 1][(size_t)(w * 64) * 8]);
      gload16(gB + kbase, &Blbuf[cur ^ 1][(size_t)(w * 64) * 8]);
    }
#pragma unroll
    for (int ks = 0; ks < 2; ++ks) {
      int sl = (ks * 4 + kb) ^ (fr & 7);
      short8 af[2], bf[2];
#pragma unroll
      for (int m = 0; m < 2; ++m)
        af[m] = *(const short8*)&Albuf[cur][((wr * 32 + m * 16 + fr) * 8 + sl) * 8];
#pragma unroll
      for (int n = 0; n < 2; ++n)
        bf[n] = *(const short8*)&Blbuf[cur][((wc * 32 + n * 16 + fr) * 8 + sl) * 8];
#pragma unroll
      for (int m = 0; m < 2; ++m)
#pragma unroll
        for (int n = 0; n < 2; ++n)
          acc[m][n] = __builtin_amdgcn_mfma_f32_16x16x32_bf16(af[m], bf[n],
                                                              acc[m][n], 0, 0, 0);
    }
    __syncthreads();   // drains this round's prefetch; next buffer ready
  }

  // ---- epilogue: positives + exp sums (C/D: row=kb*4+r, col=fr)
  int by = blockIdx.y;
  int t = by * 4 + wc;             // this wave's single t (32 cols)
  float* red = (float*)&Albuf[0][0];   // reuse LDS: [wc][wr][row32] = 2KB
#pragma unroll
  for (int m = 0; m < 2; ++m) {
    int rowg = rowbase + wr * 32 + m * 16 + kb * 4;
#pragma unroll
    for (int r = 0; r < 4; ++r) {
      int u = rowg + r;
      int b = u / 192;
      int urow = u - b * 192;
      int dt = urow - t;
      if (dt >= 0 && dt < 12) {
#pragma unroll
        for (int n = 0; n < 2; ++n) {
          int j = (wc * 32 + n * 16 + fr) & 31;
          if (j == b) pos[u * 12 + dt] = acc[m][n][r];
        }
      }
      float v = expsh(acc[m][0][r]) + expsh(acc[m][1][r]);
      v += __shfl_xor(v, 1); v += __shfl_xor(v, 2);
      v += __shfl_xor(v, 4); v += __shfl_xor(v, 8);
      if (fr == 0) {
        if (t < TAIL0) red[(wc * 4 + wr) * 32 + (m * 16 + kb * 4 + r)] = v;
        else tail[(size_t)(t - TAIL0) * NROW + u] = v;
      }
    }
  }
  __syncthreads();
  // cross-wc reduce + one plain store per row (wc==0 waves, lanes 0..31)
  int nb0 = TAIL0 - by * 4;            // #bucket0 t's in this panel
  nb0 = nb0 > 4 ? 4 : nb0;
  if (wc == 0 && nb0 > 0 && l < 32) {
    float s = 0.f;
    for (int c = 0; c < nb0; ++c) s += red[(c * 4 + wr) * 32 + l];
    partial[(size_t)by * NROW + rowbase + wr * 32 + l] = s;
  }
}

// ---- D: per-row loss terms + global reduce + fused final (completion counter)
__global__ void k_loss(const float* __restrict__ partial, const float* __restrict__ tail,
                       const float* __restrict__ pos, float* acc,
                       unsigned int* cnt, float* __restrict__ out) {
  int u = blockIdx.x * 256 + threadIdx.x;
  int urow = u % 192;
  int smax = urow < 11 ? urow : 11;
  float denom = 0.f;
  for (int g = 0; g < 46; ++g) denom += partial[(size_t)g * NROW + u];
  float local = 0.f;
  for (int s = 11; s >= 0; --s) {
    if (s < 11) denom += tail[(size_t)(10 - s) * NROW + u];
    if (s <= smax)
      local += pos[u * 12 + s] - 64.f - __logf(denom) + __logf(32.f * (float)(192 - s));
  }
  float v = local;
  v += __shfl_xor(v, 1);  v += __shfl_xor(v, 2);  v += __shfl_xor(v, 4);
  v += __shfl_xor(v, 8);  v += __shfl_xor(v, 16); v += __shfl_xor(v, 32);
  __shared__ float red[4];
  if ((threadIdx.x & 63) == 0) red[threadIdx.x >> 6] = v;
  __syncthreads();
  if (threadIdx.x == 0) {
    atomicAdd(acc, red[0] + red[1] + red[2] + red[3]);
    __threadfence();
    unsigned int old = atomicAdd(cnt, 1u);
    if (old == 23u) {   // last block: all 24 partials visible
      float tot = atomicAdd(acc, 0.0f);
      out[0] = -tot * (1.0f / NTERMS);
    }
  }
}

extern "C" void kernel_launch(void* const* d_in, const int* in_sizes, int n_in,
                              void* d_out, int out_size, void* d_ws, size_t ws_size,
                              hipStream_t stream) {
  const float* emb = (const float*)d_in[0];
  const float* ctx = (const float*)d_in[1];
  const float* W   = (const float*)d_in[2];
  char* ws = (char*)d_ws;
  ushort* P    = (ushort*)(ws + 0);         // 6144x256 bf16 = 3,145,728
  ushort* X    = (ushort*)(ws + 3145728);   // 6144x256 bf16 = 3,145,728
  ushort* Wt   = (ushort*)(ws + 6291456);   // 256x256 bf16  =   131,072
  float*  acc  = (float*)(ws + 6422528);    // 1 f32
  unsigned int* cnt = (unsigned int*)(ws + 6422532); // 1 u32
  float*  tail = (float*)(ws + 6422784);    // 11x6144 f32  =   270,336
  float*  pos  = (float*)(ws + 6693120);    // 6144x12 f32  =   294,912
  float*  partial = (float*)(ws + 6988032); // 46x6144 f32  = 1,130,496 (end ~8.12MB)

  k_castW<<<257, 256, 0, stream>>>(W, Wt, acc);
  k_projX<<<2304, 256, 0, stream>>>(emb, ctx, Wt, X, P);
  k_scores<<<dim3(48, 48), 1024, 0, stream>>>(P, X, partial, tail, pos);
  k_loss<<<24, 256, 0, stream>>>(partial, tail, pos, acc, cnt, (float*)d_out);
}

// Round 20
// 67.038 us; speedup vs baseline: 1.2563x; 1.2563x over previous
//
#include <hip/hip_runtime.h>
#include <hip/hip_bf16.h>
#include <math.h>

// B=32, T=256, E=C=256, MIN_CONTEXT=64, FUTURE_STEPS=12
// S0=192, NROW=6144, K=256. G = P·X^T (6144x6144), bucketed exp-sums.
// t in [181,192) are singleton tail buckets; bucket0 = t<181. N_terms=71616.

#define NROW 6144
#define TAIL0 181
#define NTERMS 71616.0f
#define LOG2E 1.44269504088896340736f
#define SHIFT2 92.33248261689366f   // 64 * log2(e)

typedef __attribute__((ext_vector_type(8))) short short8;
typedef __attribute__((ext_vector_type(4))) float f32x4;

__device__ __forceinline__ ushort f2bf(float f) {
  union { float f; uint32_t u; } v; v.f = f;
  uint32_t u = v.u;
  return (ushort)((u + 0x7FFFu + ((u >> 16) & 1u)) >> 16);
}
// exp(x - 64) = exp2(x*log2e - 64*log2e)
__device__ __forceinline__ float expsh(float x) {
  return exp2f(fmaf(x, LOG2E, -SHIFT2));
}

// async global->LDS, 16B per lane; lds dst must be wave-uniform base
__device__ __forceinline__ void gload16(const ushort* g, ushort* l) {
  __builtin_amdgcn_global_load_lds((const __attribute__((address_space(1))) void*)g,
                                   (__attribute__((address_space(3))) void*)l, 16, 0, 0);
}

// ---- A0+A1 fused casts + workspace zeroing (blocks >=1792).
__global__ __launch_bounds__(256) void k_cast(const float* __restrict__ ctx,
                                              const float* __restrict__ W,
                                              ushort* __restrict__ X,
                                              ushort* __restrict__ Wt,
                                              float* __restrict__ zbase) {
  int bi = blockIdx.x;
  if (bi < 1536) {
    int idx = bi * 256 + threadIdx.x;   // 393216 float4 chunks
    int row = idx >> 6, f4 = idx & 63;  // row = t*32+j
    int j = row & 31, t = row >> 5;
    float4 f = *(const float4*)(ctx + ((size_t)(j * 256 + 63 + t)) * 256 + f4 * 4);
    ushort4 o;
    o.x = f2bf(f.x); o.y = f2bf(f.y); o.z = f2bf(f.z); o.w = f2bf(f.w);
    ((ushort4*)(X + (size_t)row * 256))[f4] = o;
  } else if (bi < 1792) {
    int c = bi - 1536, e = threadIdx.x;
    Wt[c * 256 + e] = f2bf(W[e * 256 + c]);
  } else {
    int idx = (bi - 1792) * 256 + threadIdx.x;
    if (idx < 6146) zbase[idx] = 0.f;   // sum0[6144] + acc + cnt
  }
}

// ---- A2: P = emb_slice @ W (block = 16-row tile x 128-col half)
__global__ __launch_bounds__(256) void k_proj(const float* __restrict__ emb,
                                              const ushort* __restrict__ Wt,
                                              ushort* __restrict__ P) {
  __shared__ ushort Al[16 * 256];  // 8KB
  int tid = threadIdx.x;
  int rt = blockIdx.x;             // 384 row tiles
  int half = blockIdx.y;           // col half (128 cols)
#pragma unroll
  for (int q = 0; q < 4; ++q) {
    int cc = tid + q * 256;
    int rw = cc >> 6, f4 = cc & 63;
    int u = rt * 16 + rw, b = u / 192, urow = u - b * 192;
    float4 f = *(const float4*)(emb + ((size_t)(b * 256 + 64 + urow)) * 256 + f4 * 4);
    ushort4 o;
    o.x = f2bf(f.x); o.y = f2bf(f.y); o.z = f2bf(f.z); o.w = f2bf(f.w);
    int c8 = f4 >> 1;
    *(ushort4*)&Al[rw * 256 + ((c8 ^ (rw & 7)) * 8) + (f4 & 1) * 4] = o;
  }
  __syncthreads();

  int w = tid >> 6, l = tid & 63;
  int fr = l & 15, kb = l >> 4;
  short8 af[8];
#pragma unroll
  for (int kk = 0; kk < 8; ++kk) {
    int c8 = kk * 4 + kb;
    af[kk] = *(const short8*)&Al[fr * 256 + (c8 ^ (fr & 7)) * 8];
  }
#pragma unroll
  for (int i = 0; i < 2; ++i) {
    int ct = half * 8 + w * 2 + i;
    const short8* bp = (const short8*)(Wt + (size_t)(ct * 16 + fr) * 256);
    f32x4 acc = {0.f, 0.f, 0.f, 0.f};
#pragma unroll
    for (int kk = 0; kk < 8; ++kk)
      acc = __builtin_amdgcn_mfma_f32_16x16x32_bf16(af[kk], bp[kk * 4 + kb], acc, 0, 0, 0);
#pragma unroll
    for (int r = 0; r < 4; ++r)
      P[(size_t)(rt * 16 + kb * 4 + r) * 256 + ct * 16 + fr] = f2bf(acc[r]);
  }
}

// ---- B: G = P·X^T — block 128x128, 1024 thr / 16 waves, wave 32x32
// (acc[2][2] = 16 AGPR, ~40 unified regs -> 8 waves/SIMD), BK=64,
// DOUBLE-BUFFERED LDS at unchanged occupancy: 2 x (16+16) KB = 64KB ->
// 2 blocks/CU, ONE barrier per round; prefetch for round kk+1 issued BEFORE
// round kk's ds_read+MFMA so its vmcnt drain at the end-of-round barrier has
// a full round in flight (r17: 45.7us, best measured).
// LDS rows hold 8 x 16B chunks, slot XOR-swizzled (slot ^ (row&7)) via
// pre-swizzled GLOBAL source addresses -> conflict-free ds_read_b128.
// By-major grid: concurrent blocks share `by` -> disjoint atomics (r10).
__global__ __launch_bounds__(1024, 8) void k_scores(const ushort* __restrict__ P,
                                                    const ushort* __restrict__ X,
                                                    float* __restrict__ sum0,
                                                    float* __restrict__ tail,
                                                    float* __restrict__ pos) {
  __shared__ ushort Albuf[2][128 * 64];   // 2 x 16KB
  __shared__ ushort Blbuf[2][128 * 64];   // 2 x 16KB
  int tid = threadIdx.x;               // 0..1023
  int w = tid >> 6, l = tid & 63;      // w 0..15
  int wr = w >> 2, wc = w & 3;         // wr 0..3, wc 0..3
  int rowbase = blockIdx.x * 128;
  int colbase = blockIdx.y * 128;

  int fr = l & 15, kb = l >> 4;

  // staging geometry: chunk ci = tid (1024 chunks each for A and B).
  // row = ci>>3 (0..127), slot = ci&7 ; src k-chunk = slot ^ (row&7)
  int r0 = tid >> 3;
  int srcc = (tid & 7) ^ (r0 & 7);
  const ushort* gA = P + (size_t)(rowbase + r0) * 256 + srcc * 8;
  const ushort* gB = X + (size_t)(colbase + r0) * 256 + srcc * 8;

  f32x4 acc[2][2];
#pragma unroll
  for (int m = 0; m < 2; ++m)
#pragma unroll
    for (int n = 0; n < 2; ++n) acc[m][n] = {0.f, 0.f, 0.f, 0.f};

  // prologue: stage round 0 into buffer 0
  gload16(gA, &Albuf[0][(size_t)(w * 64) * 8]);
  gload16(gB, &Blbuf[0][(size_t)(w * 64) * 8]);
  __syncthreads();

  for (int kk = 0; kk < 4; ++kk) {
    int cur = kk & 1;
    if (kk < 3) {   // issue next round's stage; in flight across this round
      int kbase = (kk + 1) * 64;
      gload16(gA + kbase, &Albuf[cur ^ 1][(size_t)(w * 64) * 8]);
      gload16(gB + kbase, &Blbuf[cur ^ 1][(size_t)(w * 64) * 8]);
    }
#pragma unroll
    for (int ks = 0; ks < 2; ++ks) {
      int sl = (ks * 4 + kb) ^ (fr & 7);
      short8 af[2], bf[2];
#pragma unroll
      for (int m = 0; m < 2; ++m)
        af[m] = *(const short8*)&Albuf[cur][((wr * 32 + m * 16 + fr) * 8 + sl) * 8];
#pragma unroll
      for (int n = 0; n < 2; ++n)
        bf[n] = *(const short8*)&Blbuf[cur][((wc * 32 + n * 16 + fr) * 8 + sl) * 8];
#pragma unroll
      for (int m = 0; m < 2; ++m)
#pragma unroll
        for (int n = 0; n < 2; ++n)
          acc[m][n] = __builtin_amdgcn_mfma_f32_16x16x32_bf16(af[m], bf[n],
                                                              acc[m][n], 0, 0, 0);
    }
    __syncthreads();   // drains this round's prefetch; next buffer ready
  }

  // ---- epilogue: positives + exp bucket sums (C/D: row=kb*4+r, col=fr)
  int t = blockIdx.y * 4 + wc;     // this wave's single t (32 cols)
#pragma unroll
  for (int m = 0; m < 2; ++m) {
    int rowg = rowbase + wr * 32 + m * 16 + kb * 4;
#pragma unroll
    for (int r = 0; r < 4; ++r) {
      int u = rowg + r;
      int b = u / 192;
      int urow = u - b * 192;
      int dt = urow - t;
      if (dt >= 0 && dt < 12) {
#pragma unroll
        for (int n = 0; n < 2; ++n) {
          int j = (wc * 32 + n * 16 + fr) & 31;
          if (j == b) pos[u * 12 + dt] = acc[m][n][r];
        }
      }
      float v = expsh(acc[m][0][r]) + expsh(acc[m][1][r]);
      v += __shfl_xor(v, 1); v += __shfl_xor(v, 2);
      v += __shfl_xor(v, 4); v += __shfl_xor(v, 8);
      if (fr == 0) {
        if (t < TAIL0) atomicAdd(&sum0[u], v);
        else tail[(size_t)(t - TAIL0) * NROW + u] = v;
      }
    }
  }
}

// ---- D: per-row loss terms + global reduce + fused final (completion counter)
__global__ void k_loss(const float* __restrict__ sum0, const float* __restrict__ tail,
                       const float* __restrict__ pos, float* acc,
                       unsigned int* cnt, float* __restrict__ out) {
  int u = blockIdx.x * 256 + threadIdx.x;
  int urow = u % 192;
  int smax = urow < 11 ? urow : 11;
  float denom = sum0[u];
  float local = 0.f;
  for (int s = 11; s >= 0; --s) {
    if (s < 11) denom += tail[(size_t)(10 - s) * NROW + u];
    if (s <= smax)
      local += pos[u * 12 + s] - 64.f - __logf(denom) + __logf(32.f * (float)(192 - s));
  }
  float v = local;
  v += __shfl_xor(v, 1);  v += __shfl_xor(v, 2);  v += __shfl_xor(v, 4);
  v += __shfl_xor(v, 8);  v += __shfl_xor(v, 16); v += __shfl_xor(v, 32);
  __shared__ float red[4];
  if ((threadIdx.x & 63) == 0) red[threadIdx.x >> 6] = v;
  __syncthreads();
  if (threadIdx.x == 0) {
    atomicAdd(acc, red[0] + red[1] + red[2] + red[3]);
    __threadfence();
    unsigned int old = atomicAdd(cnt, 1u);
    if (old == 23u) {   // last block: all 24 partials visible
      float tot = atomicAdd(acc, 0.0f);
      out[0] = -tot * (1.0f / NTERMS);
    }
  }
}

extern "C" void kernel_launch(void* const* d_in, const int* in_sizes, int n_in,
                              void* d_out, int out_size, void* d_ws, size_t ws_size,
                              hipStream_t stream) {
  const float* emb = (const float*)d_in[0];
  const float* ctx = (const float*)d_in[1];
  const float* W   = (const float*)d_in[2];
  char* ws = (char*)d_ws;
  ushort* P    = (ushort*)(ws + 0);         // 6144x256 bf16
  ushort* X    = (ushort*)(ws + 3145728);   // 6144x256 bf16
  ushort* Wt   = (ushort*)(ws + 6291456);   // 256x256 bf16
  float*  sum0 = (float*)(ws + 6422528);    // 6144 f32
  float*  acc  = (float*)(ws + 6447104);    // 1 f32   (= sum0+6144)
  unsigned int* cnt = (unsigned int*)(ws + 6447108); // 1 u32 (= sum0+6145)
  float*  tail = (float*)(ws + 6447360);    // 11x6144 f32
  float*  pos  = (float*)(ws + 6717696);    // 6144x12 f32

  k_cast<<<1817, 256, 0, stream>>>(ctx, W, X, Wt, sum0);
  k_proj<<<dim3(384, 2), 256, 0, stream>>>(emb, Wt, P);
  k_scores<<<dim3(48, 48), 1024, 0, stream>>>(P, X, sum0, tail, pos);
  k_loss<<<24, 256, 0, stream>>>(sum0, tail, pos, acc, cnt, (float*)d_out);
}